// Round 1
// baseline (8440.099 us; speedup 1.0000x reference)
//
#include <hip/hip_runtime.h>
#include <math.h>

#define TT   256
#define FF   32
#define CCH  8
#define VV   10000
#define HH   1024
#define EE   256
#define KTOT 1280
#define EOS_ID 2

// ---------------------------------------------------------------------------
// prep: decoder input ids c_in[t][f] and entry-time done flags done[t][f]
// ---------------------------------------------------------------------------
__global__ __launch_bounds__(256) void prep_kernel(const int* __restrict__ oc,
                                                   int* __restrict__ c_in,
                                                   unsigned char* __restrict__ done) {
    int t = threadIdx.x;            // T == 256 threads
    int c0 = oc[0];
    bool d = (c0 == EOS_ID);
    for (int f = 0; f < FF; ++f) {
        c_in[t * FF + f] = (f == 0) ? c0 : oc[1 + t * FF + f - 1];
        done[t * FF + f] = d ? 1 : 0;
        d = d || (oc[1 + t * FF + f] == EOS_ID);
    }
}

// ---------------------------------------------------------------------------
// h0[t][j] = mean_c token_ctx[ xtoken_ids[t][c] ][j]
// ---------------------------------------------------------------------------
__global__ __launch_bounds__(256) void h0_kernel(const float* __restrict__ tctx,
                                                 const int* __restrict__ sent,
                                                 float* __restrict__ h) {
    int t = blockIdx.x;
    __shared__ int xt[CCH];
    if (threadIdx.x < CCH) xt[threadIdx.x] = sent[(t * CCH + threadIdx.x) * 3 + 1];
    __syncthreads();
    for (int j = threadIdx.x; j < HH; j += 256) {
        float s = 0.f;
#pragma unroll
        for (int c = 0; c < CCH; ++c) s += tctx[xt[c] * HH + j];
        h[t * HH + j] = s * 0.125f;
    }
}

// ---------------------------------------------------------------------------
// One GRU step. A = [emb(id) | h]  (T x 1280),  B = [W_ih | W_hh] rows for
// gates r/z/n.  Block computes a 32(T) x 32(H) tile of h_new, fused epilogue.
// grid = (8, 32), 256 threads.
// ---------------------------------------------------------------------------
__global__ __launch_bounds__(256) void gru_step(
    const float* __restrict__ emb,
    const int* __restrict__ ids, int ids_stride, int ids_off,
    const float* __restrict__ h_in, float* __restrict__ h_out,
    const float* __restrict__ W_ih, const float* __restrict__ W_hh,
    const float* __restrict__ b_ih, const float* __restrict__ b_hh,
    const unsigned char* __restrict__ done, int done_off) {

    __shared__ float As[16][36];
    __shared__ float Br[16][36], Bz[16][36], Bn[16][36];
    __shared__ int sids[32];

    const int tid = threadIdx.x;
    const int t0 = blockIdx.x * 32;
    const int n0 = blockIdx.y * 32;

    if (tid < 32) sids[tid] = ids[(t0 + tid) * ids_stride + ids_off];

    const int li  = tid >> 4;        // 0..15 (stage row)
    const int lk  = tid & 15;        // 0..15 (stage k)
    const int row = 2 * (tid >> 4);  // 0..30 (compute rows)
    const int col = 2 * (tid & 15);  // 0..30 (compute cols)

    float ar[4] = {0.f, 0.f, 0.f, 0.f};
    float az[4] = {0.f, 0.f, 0.f, 0.f};
    float an[4] = {0.f, 0.f, 0.f, 0.f};
    float ah[4] = {0.f, 0.f, 0.f, 0.f};

    for (int k0 = 0; k0 < KTOT; k0 += 16) {
        __syncthreads();
        {
            const int kg = k0 + lk;
            const bool xp = (kg < EE);
#pragma unroll
            for (int rr = 0; rr < 2; ++rr) {
                const int i = li + rr * 16;
                float va;
                if (xp) va = emb[sids[i] * EE + kg];
                else    va = h_in[(t0 + i) * HH + (kg - EE)];
                As[lk][i] = va;
                const int wr = n0 + i;
                float vr, vz, vn;
                if (xp) {
                    vr = W_ih[(0 * HH + wr) * EE + kg];
                    vz = W_ih[(1 * HH + wr) * EE + kg];
                    vn = W_ih[(2 * HH + wr) * EE + kg];
                } else {
                    vr = W_hh[(0 * HH + wr) * HH + (kg - EE)];
                    vz = W_hh[(1 * HH + wr) * HH + (kg - EE)];
                    vn = W_hh[(2 * HH + wr) * HH + (kg - EE)];
                }
                Br[lk][i] = vr; Bz[lk][i] = vz; Bn[lk][i] = vn;
            }
        }
        __syncthreads();

        if (k0 < EE) {  // x-part: n-gate accumulates into an[] (i_n)
#pragma unroll
            for (int kk = 0; kk < 16; ++kk) {
                const float2 a  = *(const float2*)&As[kk][row];
                const float2 br = *(const float2*)&Br[kk][col];
                const float2 bz = *(const float2*)&Bz[kk][col];
                const float2 bn = *(const float2*)&Bn[kk][col];
                ar[0] += a.x * br.x; ar[1] += a.x * br.y; ar[2] += a.y * br.x; ar[3] += a.y * br.y;
                az[0] += a.x * bz.x; az[1] += a.x * bz.y; az[2] += a.y * bz.x; az[3] += a.y * bz.y;
                an[0] += a.x * bn.x; an[1] += a.x * bn.y; an[2] += a.y * bn.x; an[3] += a.y * bn.y;
            }
        } else {        // h-part: n-gate accumulates into ah[] (h_n)
#pragma unroll
            for (int kk = 0; kk < 16; ++kk) {
                const float2 a  = *(const float2*)&As[kk][row];
                const float2 br = *(const float2*)&Br[kk][col];
                const float2 bz = *(const float2*)&Bz[kk][col];
                const float2 bn = *(const float2*)&Bn[kk][col];
                ar[0] += a.x * br.x; ar[1] += a.x * br.y; ar[2] += a.y * br.x; ar[3] += a.y * br.y;
                az[0] += a.x * bz.x; az[1] += a.x * bz.y; az[2] += a.y * bz.x; az[3] += a.y * bz.y;
                ah[0] += a.x * bn.x; ah[1] += a.x * bn.y; ah[2] += a.y * bn.x; ah[3] += a.y * bn.y;
            }
        }
    }

#pragma unroll
    for (int di = 0; di < 2; ++di) {
        const int t = t0 + row + di;
        const unsigned char dn = done ? done[t * FF + done_off] : (unsigned char)0;
#pragma unroll
        for (int dj = 0; dj < 2; ++dj) {
            const int j = n0 + col + dj;
            const int q = di * 2 + dj;
            const float rr = ar[q] + b_ih[j] + b_hh[j];
            const float zz = az[q] + b_ih[HH + j] + b_hh[HH + j];
            const float r  = 1.f / (1.f + __expf(-rr));
            const float z  = 1.f / (1.f + __expf(-zz));
            const float nn = tanhf(an[q] + b_ih[2 * HH + j] + r * (ah[q] + b_hh[2 * HH + j]));
            const float hold = h_in[t * HH + j];
            float hv = (1.f - z) * nn + z * hold;
            if (dn) hv = hold;
            h_out[t * HH + j] = hv;
        }
    }
}

// ---------------------------------------------------------------------------
// scores: out[(t*F+f)*V + v] = hs[f*T+t] . out_W[v] + out_b[v]
// hs = (F*T, H).  Tile 64(M) x 128(N), BK=16, 256 threads, 4x8 per thread.
// k-major LDS so fragment reads are b128/b64, <=2-way bank aliasing.
// ---------------------------------------------------------------------------
__global__ __launch_bounds__(256) void scores_kernel(
    const float* __restrict__ hs, const float* __restrict__ Wout,
    const float* __restrict__ bout, const int* __restrict__ oc,
    float* __restrict__ out) {

    __shared__ float As[16][68];    // row stride 272B (16B aligned)
    __shared__ float Bs[16][136];   // row stride 544B (16B aligned)

    const int tid = threadIdx.x;
    const int v0 = blockIdx.x * 128;
    const int m0 = blockIdx.y * 64;

    // staging coords
    const int lrA = tid >> 2;            // 0..63 row of A tile
    const int lqA = tid & 3;             // quad
    const int lrB = tid >> 1;            // 0..127 row of B tile
    const int lqB0 = (tid & 1) * 2;      // quads lqB0, lqB0+1

    // compute coords
    const int r0 = 4 * (tid >> 4);       // A rows (broadcast within 16 lanes)
    const int cA = 4 * (tid & 15);       // B cols group 0
    // group 1 at cA + 64

    float acc[4][8];
#pragma unroll
    for (int i = 0; i < 4; ++i)
#pragma unroll
        for (int j = 0; j < 8; ++j) acc[i][j] = 0.f;

    const float* aptr = &hs[(m0 + lrA) * HH];
    const int vB0 = v0 + lrB;
    const float* bptr = &Wout[(size_t)vB0 * HH];
    const bool bok = (vB0 < VV);

    for (int k0 = 0; k0 < HH; k0 += 16) {
        __syncthreads();
        {
            const float4 a = *(const float4*)(aptr + k0 + lqA * 4);
            As[lqA * 4 + 0][lrA] = a.x;
            As[lqA * 4 + 1][lrA] = a.y;
            As[lqA * 4 + 2][lrA] = a.z;
            As[lqA * 4 + 3][lrA] = a.w;
#pragma unroll
            for (int jj = 0; jj < 2; ++jj) {
                const int lq = lqB0 + jj;
                float4 b;
                if (bok) b = *(const float4*)(bptr + k0 + lq * 4);
                else     b = make_float4(0.f, 0.f, 0.f, 0.f);
                Bs[lq * 4 + 0][lrB] = b.x;
                Bs[lq * 4 + 1][lrB] = b.y;
                Bs[lq * 4 + 2][lrB] = b.z;
                Bs[lq * 4 + 3][lrB] = b.w;
            }
        }
        __syncthreads();

#pragma unroll
        for (int kk = 0; kk < 16; ++kk) {
            const float4 av = *(const float4*)&As[kk][r0];
            const float4 b0 = *(const float4*)&Bs[kk][cA];
            const float4 b1 = *(const float4*)&Bs[kk][cA + 64];
            acc[0][0] += av.x * b0.x; acc[0][1] += av.x * b0.y; acc[0][2] += av.x * b0.z; acc[0][3] += av.x * b0.w;
            acc[0][4] += av.x * b1.x; acc[0][5] += av.x * b1.y; acc[0][6] += av.x * b1.z; acc[0][7] += av.x * b1.w;
            acc[1][0] += av.y * b0.x; acc[1][1] += av.y * b0.y; acc[1][2] += av.y * b0.z; acc[1][3] += av.y * b0.w;
            acc[1][4] += av.y * b1.x; acc[1][5] += av.y * b1.y; acc[1][6] += av.y * b1.z; acc[1][7] += av.y * b1.w;
            acc[2][0] += av.z * b0.x; acc[2][1] += av.z * b0.y; acc[2][2] += av.z * b0.z; acc[2][3] += av.z * b0.w;
            acc[2][4] += av.z * b1.x; acc[2][5] += av.z * b1.y; acc[2][6] += av.z * b1.z; acc[2][7] += av.z * b1.w;
            acc[3][0] += av.w * b0.x; acc[3][1] += av.w * b0.y; acc[3][2] += av.w * b0.z; acc[3][3] += av.w * b0.w;
            acc[3][4] += av.w * b1.x; acc[3][5] += av.w * b1.y; acc[3][6] += av.w * b1.z; acc[3][7] += av.w * b1.w;
        }
    }

    const int c0eos = (oc[0] == EOS_ID) ? 1 : 0;
#pragma unroll
    for (int i = 0; i < 4; ++i) {
        const int m = m0 + r0 + i;
        const int f = m >> 8;          // m / T
        const int t = m & 255;         // m % T
        float* orow = out + (size_t)(t * FF + f) * VV;
#pragma unroll
        for (int j = 0; j < 8; ++j) {
            const int v = v0 + cA + (j >> 2) * 64 + (j & 3);
            if (v < VV) {
                const float val = acc[i][j] + bout[v];
                orow[v] = c0eos ? 0.f : val;
            }
        }
    }
}

// ---------------------------------------------------------------------------
extern "C" void kernel_launch(void* const* d_in, const int* in_sizes, int n_in,
                              void* d_out, int out_size, void* d_ws, size_t ws_size,
                              hipStream_t stream) {
    (void)in_sizes; (void)n_in; (void)out_size; (void)ws_size;

    const float* token_ctx = (const float*)d_in[0];
    const float* emb       = (const float*)d_in[1];
    const float* eWih      = (const float*)d_in[2];
    const float* eWhh      = (const float*)d_in[3];
    const float* ebih      = (const float*)d_in[4];
    const float* ebhh      = (const float*)d_in[5];
    const float* dWih      = (const float*)d_in[6];
    const float* dWhh      = (const float*)d_in[7];
    const float* dbih      = (const float*)d_in[8];
    const float* dbhh      = (const float*)d_in[9];
    const float* Wout      = (const float*)d_in[10];
    const float* bout      = (const float*)d_in[11];
    const int*   sent      = (const int*)d_in[12];
    const int*   ochars    = (const int*)d_in[13];
    float* out = (float*)d_out;

    // workspace layout (all fp32 unless noted)
    float* hA   = (float*)d_ws;                       // (T,H)
    float* hB   = hA + TT * HH;                       // (T,H)
    float* hs   = hB + TT * HH;                       // (F,T,H)
    int*   c_in = (int*)(hs + FF * TT * HH);          // (T,F)
    unsigned char* done = (unsigned char*)(c_in + TT * FF); // (T,F)

    prep_kernel<<<1, 256, 0, stream>>>(ochars, c_in, done);
    h0_kernel<<<TT, 256, 0, stream>>>(token_ctx, sent, hA);

    dim3 ggrid(8, 32);
    // encoder: 8 steps, ping-pong hA <-> hB, ends in hA
    for (int c = 0; c < CCH; ++c) {
        const float* hin = (c & 1) ? hB : hA;
        float* hout      = (c & 1) ? hA : hB;
        gru_step<<<ggrid, 256, 0, stream>>>(emb, sent, CCH * 3, c * 3 + 2,
                                            hin, hout, eWih, eWhh, ebih, ebhh,
                                            nullptr, 0);
    }
    // decoder: 32 steps, h chain through hs; freeze via done flags
    for (int f = 0; f < FF; ++f) {
        const float* hin = (f == 0) ? hA : (hs + (size_t)(f - 1) * TT * HH);
        float* hout      = hs + (size_t)f * TT * HH;
        gru_step<<<ggrid, 256, 0, stream>>>(emb, c_in, FF, f,
                                            hin, hout, dWih, dWhh, dbih, dbhh,
                                            done, f);
    }

    dim3 sgrid(79, 128);   // ceil(10000/128) x (8192/64)
    scores_kernel<<<sgrid, 256, 0, stream>>>(hs, Wout, bout, ochars, out);
}

// Round 2
// 3351.195 us; speedup vs baseline: 2.5185x; 2.5185x over previous
//
#include <hip/hip_runtime.h>
#include <hip/hip_bf16.h>
#include <math.h>

#define TT   256
#define FF   32
#define CCH  8
#define VV   10000
#define HH   1024
#define EE   256
#define KSTEP 3328      // 256 (x) + 1024 (h_hi) + 1024 (h_lo) + 1024 (h_hi dup)
#define NSTEP 4096      // gate cols: r | z | i_n | h_n
#define EOS_ID 2

typedef __attribute__((ext_vector_type(8))) short bf16x8;
typedef __attribute__((ext_vector_type(4))) float f32x4;

__device__ __forceinline__ void gload_lds16(const void* g, void* l) {
    __builtin_amdgcn_global_load_lds((const __attribute__((address_space(1))) void*)g,
                                     (__attribute__((address_space(3))) void*)l,
                                     16, 0, 0);
}

// ---------------------------------------------------------------------------
// prep: decoder input ids c_in[t][f] and entry-time done flags done[t][f]
// ---------------------------------------------------------------------------
__global__ __launch_bounds__(256) void prep_kernel(const int* __restrict__ oc,
                                                   int* __restrict__ c_in,
                                                   unsigned char* __restrict__ done) {
    int t = threadIdx.x;
    int c0 = oc[0];
    bool d = (c0 == EOS_ID);
    for (int f = 0; f < FF; ++f) {
        c_in[t * FF + f] = (f == 0) ? c0 : oc[1 + t * FF + f - 1];
        done[t * FF + f] = d ? 1 : 0;
        d = d || (oc[1 + t * FF + f] == EOS_ID);
    }
}

// ---------------------------------------------------------------------------
// h0 + assemble A0 = [x0 | h0_hi | h0_lo | h0_hi]
// ---------------------------------------------------------------------------
__global__ __launch_bounds__(256) void h0_kernel(const float* __restrict__ tctx,
                                                 const int* __restrict__ sent,
                                                 const float* __restrict__ emb,
                                                 float* __restrict__ h,
                                                 __hip_bfloat16* __restrict__ A0) {
    int t = blockIdx.x;
    int tid = threadIdx.x;
    __shared__ int xt[CCH];
    if (tid < CCH) xt[tid] = sent[(t * CCH + tid) * 3 + 1];
    __syncthreads();
    {   // x-part: chars at c=0
        int c0 = sent[(t * CCH + 0) * 3 + 2];
        A0[(size_t)t * KSTEP + tid] = __float2bfloat16(emb[(size_t)c0 * EE + tid]);
    }
#pragma unroll
    for (int jj = 0; jj < 4; ++jj) {
        int j = tid + jj * 256;
        float s = 0.f;
#pragma unroll
        for (int c = 0; c < CCH; ++c) s += tctx[(size_t)xt[c] * HH + j];
        float hv = s * 0.125f;
        h[(size_t)t * HH + j] = hv;
        __hip_bfloat16 hi = __float2bfloat16(hv);
        __hip_bfloat16 lo = __float2bfloat16(hv - __bfloat162float(hi));
        A0[(size_t)t * KSTEP + 256 + j]  = hi;
        A0[(size_t)t * KSTEP + 1280 + j] = lo;
        A0[(size_t)t * KSTEP + 2304 + j] = hi;
    }
}

// ---------------------------------------------------------------------------
// Wout fp32 -> bf16
// ---------------------------------------------------------------------------
__global__ __launch_bounds__(256) void conv_wout(const float* __restrict__ W,
                                                 __hip_bfloat16* __restrict__ Wb) {
    size_t base = ((size_t)blockIdx.x * 256 + threadIdx.x) * 4;
    float4 v = *(const float4*)(W + base);
    Wb[base + 0] = __float2bfloat16(v.x);
    Wb[base + 1] = __float2bfloat16(v.y);
    Wb[base + 2] = __float2bfloat16(v.z);
    Wb[base + 3] = __float2bfloat16(v.w);
}

// ---------------------------------------------------------------------------
// Build B (NSTEP x KSTEP bf16):
//  cols(k): [Wih | Whh_hi | Whh_hi | Whh_lo]; rows(n): gates r|z|i_n|h_n
//  i_n rows zero for k>=256; h_n rows zero for k<256.
//  grid (13, 4096), 256 threads: k = bx*256+tid, n = by
// ---------------------------------------------------------------------------
__global__ __launch_bounds__(256) void build_B(const float* __restrict__ Wih,
                                               const float* __restrict__ Whh,
                                               __hip_bfloat16* __restrict__ Bw) {
    int k = blockIdx.x * 256 + threadIdx.x;
    int n = blockIdx.y;
    int g = n >> 10, j = n & 1023;
    __hip_bfloat16 outv;
    if (k < 256) {
        float val = (g == 3) ? 0.f : Wih[(size_t)(g * 1024 + j) * EE + k];
        outv = __float2bfloat16(val);
    } else if (g == 2) {
        outv = __float2bfloat16(0.f);
    } else {
        int seg = (k - 256) >> 10;
        int kk  = (k - 256) & 1023;
        int gr  = (g == 3) ? 2 : g;
        float wv = Whh[(size_t)(gr * 1024 + j) * HH + kk];
        __hip_bfloat16 hi = __float2bfloat16(wv);
        outv = (seg < 2) ? hi : __float2bfloat16(wv - __bfloat162float(hi));
    }
    Bw[(size_t)n * KSTEP + k] = outv;
}

// ---------------------------------------------------------------------------
// 128x128 MFMA GEMM core (m97 structure). C = A(MxK) * B(NxK)^T.
// Both A and B row-major, K contiguous. BK=32, 4 waves, 4x4 frags/wave.
// ---------------------------------------------------------------------------
template<bool CLAMPB>
__device__ __forceinline__ void gemm128_core(const __hip_bfloat16* __restrict__ A, int lda,
                                             const __hip_bfloat16* __restrict__ B, int ldb,
                                             int K, int m0, int n0, int maxBrow,
                                             __hip_bfloat16* As, __hip_bfloat16* Bs,
                                             f32x4 acc[4][4]) {
    const int tid = threadIdx.x;
    const int l = tid & 63;
    const int w = tid >> 6;
    const int wr = (w >> 1) * 64, wc = (w & 1) * 64;

    // staging: round i covers LDS bytes [i*4096, i*4096+4096), thread byte = i*4096 + tid*16
    const int srow = tid >> 2;       // tile row (+64 for round 1)
    const int skq  = tid & 3;        // which 16B chunk of the 64B row

    const int ar0 = m0 + srow, ar1 = m0 + 64 + srow;
    int br0 = n0 + srow, br1 = n0 + 64 + srow;
    if (CLAMPB) {
        br0 = (br0 > maxBrow) ? maxBrow : br0;
        br1 = (br1 > maxBrow) ? maxBrow : br1;
    }
    const __hip_bfloat16* gA0 = A + (size_t)ar0 * lda + skq * 8;
    const __hip_bfloat16* gA1 = A + (size_t)ar1 * lda + skq * 8;
    const __hip_bfloat16* gB0 = B + (size_t)br0 * ldb + skq * 8;
    const __hip_bfloat16* gB1 = B + (size_t)br1 * ldb + skq * 8;
    __hip_bfloat16* lA = As + tid * 8;
    __hip_bfloat16* lB = Bs + tid * 8;

    const int fra = ((wr + (l & 15)) << 5) + ((l >> 4) << 3);
    const int frb = ((wc + (l & 15)) << 5) + ((l >> 4) << 3);

    for (int k0 = 0; k0 < K; k0 += 32) {
        __syncthreads();
        gload_lds16(gA0 + k0, lA);
        gload_lds16(gA1 + k0, lA + 2048);
        gload_lds16(gB0 + k0, lB);
        gload_lds16(gB1 + k0, lB + 2048);
        __syncthreads();
        bf16x8 af[4], bfv[4];
#pragma unroll
        for (int fm = 0; fm < 4; ++fm) af[fm] = *(const bf16x8*)&As[fra + fm * 512];
#pragma unroll
        for (int fn = 0; fn < 4; ++fn) bfv[fn] = *(const bf16x8*)&Bs[frb + fn * 512];
#pragma unroll
        for (int fm = 0; fm < 4; ++fm)
#pragma unroll
            for (int fn = 0; fn < 4; ++fn)
                acc[fm][fn] = __builtin_amdgcn_mfma_f32_16x16x32_bf16(af[fm], bfv[fn], acc[fm][fn], 0, 0, 0);
    }
}

// ---------------------------------------------------------------------------
// scores: hs_bf16 (8192x1024) x Wout_bf16 (10000x1024)^T + bias -> out
// grid 5056 (79 N x 64 M), XCD-swizzled
// ---------------------------------------------------------------------------
__global__ __launch_bounds__(256) void scores_mfma(const __hip_bfloat16* __restrict__ hsb,
                                                   const __hip_bfloat16* __restrict__ Wb,
                                                   const float* __restrict__ bout,
                                                   const int* __restrict__ oc,
                                                   float* __restrict__ out) {
    __shared__ __hip_bfloat16 As[128 * 32], Bs[128 * 32];
    int bid = blockIdx.x;
    int sid = (bid & 7) * 632 + (bid >> 3);      // 5056 = 8*632, bijective
    int bx = sid % 79, by = sid / 79;
    int n0 = bx * 128, m0 = by * 128;

    f32x4 acc[4][4];
#pragma unroll
    for (int i = 0; i < 4; ++i)
#pragma unroll
        for (int j = 0; j < 4; ++j) acc[i][j] = (f32x4){0.f, 0.f, 0.f, 0.f};

    gemm128_core<true>(hsb, HH, Wb, HH, HH, m0, n0, VV - 1, As, Bs, acc);

    const bool zf = (oc[0] == EOS_ID);
    const int l = threadIdx.x & 63, w = threadIdx.x >> 6;
    const int wr = (w >> 1) * 64, wc = (w & 1) * 64;
    const int colb = wc + (l & 15);
    const int rb   = wr + ((l >> 4) << 2);
#pragma unroll
    for (int fn = 0; fn < 4; ++fn) {
        int v = n0 + colb + fn * 16;
        if (v < VV) {
            float bb = bout[v];
#pragma unroll
            for (int fm = 0; fm < 4; ++fm) {
#pragma unroll
                for (int q = 0; q < 4; ++q) {
                    int m = m0 + rb + fm * 16 + q;
                    int f = m >> 8, t = m & 255;
                    out[(size_t)(t * FF + f) * VV + v] = zf ? 0.f : (acc[fm][fn][q] + bb);
                }
            }
        }
    }
}

// ---------------------------------------------------------------------------
// per-step GEMM: A (256 x 3328) x B (4096 x 3328)^T -> gh (256 x 4096) fp32
// grid (32, 2)
// ---------------------------------------------------------------------------
__global__ __launch_bounds__(256) void step_gemm(const __hip_bfloat16* __restrict__ Astep,
                                                 const __hip_bfloat16* __restrict__ Bw,
                                                 float* __restrict__ gh) {
    __shared__ __hip_bfloat16 As[128 * 32], Bs[128 * 32];
    int n0 = blockIdx.x * 128;
    int m0 = blockIdx.y * 128;

    f32x4 acc[4][4];
#pragma unroll
    for (int i = 0; i < 4; ++i)
#pragma unroll
        for (int j = 0; j < 4; ++j) acc[i][j] = (f32x4){0.f, 0.f, 0.f, 0.f};

    gemm128_core<false>(Astep, KSTEP, Bw, KSTEP, KSTEP, m0, n0, 0, As, Bs, acc);

    const int l = threadIdx.x & 63, w = threadIdx.x >> 6;
    const int wr = (w >> 1) * 64, wc = (w & 1) * 64;
    const int colb = wc + (l & 15);
    const int rb   = wr + ((l >> 4) << 2);
#pragma unroll
    for (int fm = 0; fm < 4; ++fm)
#pragma unroll
        for (int fn = 0; fn < 4; ++fn)
#pragma unroll
            for (int q = 0; q < 4; ++q)
                gh[(size_t)(m0 + rb + fm * 16 + q) * NSTEP + n0 + colb + fn * 16] = acc[fm][fn][q];
}

// ---------------------------------------------------------------------------
// GRU epilogue: gates -> h_out (fp32), A_next h-parts + x-part, hs_bf16 slice
// grid 256 (t), 256 threads
// ---------------------------------------------------------------------------
__global__ __launch_bounds__(256) void gru_epi(const float* __restrict__ gh,
                                               const float* __restrict__ bih,
                                               const float* __restrict__ bhh,
                                               const float* __restrict__ h_in,
                                               float* __restrict__ h_out,
                                               __hip_bfloat16* __restrict__ A_next,
                                               const float* __restrict__ emb,
                                               const int* __restrict__ nids, int nstr, int noff,
                                               __hip_bfloat16* __restrict__ hs_out,
                                               const unsigned char* __restrict__ dflags, int doff) {
    int t = blockIdx.x, tid = threadIdx.x;
    unsigned char dn = dflags ? dflags[t * FF + doff] : (unsigned char)0;
    if (A_next) {   // x-part for next step
        int nid = nids[t * nstr + noff];
        A_next[(size_t)t * KSTEP + tid] = __float2bfloat16(emb[(size_t)nid * EE + tid]);
    }
#pragma unroll
    for (int jj = 0; jj < 4; ++jj) {
        int j = tid + jj * 256;
        float rr = gh[(size_t)t * NSTEP + j]          + bih[j]        + bhh[j];
        float zz = gh[(size_t)t * NSTEP + 1024 + j]   + bih[1024 + j] + bhh[1024 + j];
        float ii = gh[(size_t)t * NSTEP + 2048 + j]   + bih[2048 + j];
        float hn = gh[(size_t)t * NSTEP + 3072 + j]   + bhh[2048 + j];
        float r = 1.f / (1.f + __expf(-rr));
        float z = 1.f / (1.f + __expf(-zz));
        float n = tanhf(ii + r * hn);
        float hold = h_in[(size_t)t * HH + j];
        float hv = (1.f - z) * n + z * hold;
        if (dn) hv = hold;
        h_out[(size_t)t * HH + j] = hv;
        __hip_bfloat16 hi = __float2bfloat16(hv);
        __hip_bfloat16 lo = __float2bfloat16(hv - __bfloat162float(hi));
        if (A_next) {
            A_next[(size_t)t * KSTEP + 256 + j]  = hi;
            A_next[(size_t)t * KSTEP + 1280 + j] = lo;
            A_next[(size_t)t * KSTEP + 2304 + j] = hi;
        }
        if (hs_out) hs_out[(size_t)t * HH + j] = hi;
    }
}

// ---------------------------------------------------------------------------
extern "C" void kernel_launch(void* const* d_in, const int* in_sizes, int n_in,
                              void* d_out, int out_size, void* d_ws, size_t ws_size,
                              hipStream_t stream) {
    (void)in_sizes; (void)n_in; (void)ws_size;

    const float* token_ctx = (const float*)d_in[0];
    const float* emb       = (const float*)d_in[1];
    const float* eWih      = (const float*)d_in[2];
    const float* eWhh      = (const float*)d_in[3];
    const float* ebih      = (const float*)d_in[4];
    const float* ebhh      = (const float*)d_in[5];
    const float* dWih      = (const float*)d_in[6];
    const float* dWhh      = (const float*)d_in[7];
    const float* dbih      = (const float*)d_in[8];
    const float* dbhh      = (const float*)d_in[9];
    const float* Wout      = (const float*)d_in[10];
    const float* bout      = (const float*)d_in[11];
    const int*   sent      = (const int*)d_in[12];
    const int*   ochars    = (const int*)d_in[13];
    float* out = (float*)d_out;

    // ---- workspace layout (all 256B-aligned by construction) ----
    char* w = (char*)d_ws;
    float* hA = (float*)w;                         w += (size_t)TT * HH * 4;        // 1 MB
    float* hB = (float*)w;                         w += (size_t)TT * HH * 4;        // 1 MB
    float* gh = (float*)w;                         w += (size_t)TT * NSTEP * 4;     // 4 MB
    __hip_bfloat16* A0 = (__hip_bfloat16*)w;       w += (size_t)TT * KSTEP * 2;     // 1.7 MB
    __hip_bfloat16* A1 = (__hip_bfloat16*)w;       w += (size_t)TT * KSTEP * 2;     // 1.7 MB
    __hip_bfloat16* Woutb = (__hip_bfloat16*)w;    w += (size_t)VV * HH * 2;        // 20.5 MB
    __hip_bfloat16* hsb = (__hip_bfloat16*)w;      w += (size_t)FF * TT * HH * 2;   // 16.8 MB
    int* c_in = (int*)w;                           w += (size_t)TT * FF * 4;
    unsigned char* done = (unsigned char*)w;

    // B matrices live in the tail of d_out (dead before scores writes out)
    const size_t B_BYTES = (size_t)NSTEP * KSTEP * 2;    // 27.26 MB
    __hip_bfloat16* Benc = (__hip_bfloat16*)((char*)d_out + (size_t)out_size * 4 - 2 * B_BYTES);
    __hip_bfloat16* Bdec = Benc + (size_t)NSTEP * KSTEP;

    // ---- prep ----
    prep_kernel<<<1, 256, 0, stream>>>(ochars, c_in, done);
    h0_kernel<<<TT, 256, 0, stream>>>(token_ctx, sent, emb, hA, A0);
    conv_wout<<<(VV * HH) / 4 / 256, 256, 0, stream>>>(Wout, Woutb);
    build_B<<<dim3(13, NSTEP), 256, 0, stream>>>(eWih, eWhh, Benc);
    build_B<<<dim3(13, NSTEP), 256, 0, stream>>>(dWih, dWhh, Bdec);

    // ---- encoder: 8 steps ----
    dim3 sg(32, 2);
    const float* hcur = hA; float* hnext = hB;
    __hip_bfloat16* Acur = A0; __hip_bfloat16* Anext = A1;
    for (int c = 0; c < CCH; ++c) {
        step_gemm<<<sg, 256, 0, stream>>>(Acur, Benc, gh);
        const int* nids; int nstr, noff;
        if (c < CCH - 1) { nids = sent; nstr = CCH * 3; noff = (c + 1) * 3 + 2; }
        else             { nids = c_in; nstr = FF;      noff = 0; }
        gru_epi<<<TT, 256, 0, stream>>>(gh, ebih, ebhh, hcur, hnext, Anext,
                                        emb, nids, nstr, noff, nullptr, nullptr, 0);
        const float* tmp = hcur; hcur = hnext; hnext = (float*)tmp;
        __hip_bfloat16* tA = Acur; Acur = Anext; Anext = tA;
    }
    // ---- decoder: 32 steps ----
    for (int f = 0; f < FF; ++f) {
        step_gemm<<<sg, 256, 0, stream>>>(Acur, Bdec, gh);
        __hip_bfloat16* An = (f < FF - 1) ? Anext : nullptr;
        gru_epi<<<TT, 256, 0, stream>>>(gh, dbih, dbhh, hcur, hnext, An,
                                        emb, c_in, FF, f + 1,
                                        hsb + (size_t)f * TT * HH, done, f);
        const float* tmp = hcur; hcur = hnext; hnext = (float*)tmp;
        __hip_bfloat16* tA = Acur; Acur = Anext; Anext = tA;
    }

    // ---- scores ----
    scores_mfma<<<5056, 256, 0, stream>>>(hsb, Woutb, bout, ochars, out);
}

// Round 3
// 1330.166 us; speedup vs baseline: 6.3451x; 2.5194x over previous
//
#include <hip/hip_runtime.h>
#include <hip/hip_bf16.h>
#include <math.h>

#define TT   256
#define FF   32
#define CCH  8
#define VV   10000
#define HH   1024
#define EE   256
#define NG   3072        // gate cols r|z|n
#define KH   2048        // [h_hi | h_lo]
#define EOS_ID 2

typedef __attribute__((ext_vector_type(8))) short bf16x8;
typedef __attribute__((ext_vector_type(4))) float f32x4;

__device__ __forceinline__ void gload_lds16(const void* g, void* l) {
    __builtin_amdgcn_global_load_lds((const __attribute__((address_space(1))) void*)g,
                                     (__attribute__((address_space(3))) void*)l,
                                     16, 0, 0);
}

// ---------------------------------------------------------------------------
// prep: decoder input ids c_in[t][f] and entry-time done flags done[t][f]
// ---------------------------------------------------------------------------
__global__ __launch_bounds__(256) void prep_kernel(const int* __restrict__ oc,
                                                   int* __restrict__ c_in,
                                                   unsigned char* __restrict__ done) {
    int t = threadIdx.x;
    int c0 = oc[0];
    bool d = (c0 == EOS_ID);
    for (int f = 0; f < FF; ++f) {
        c_in[t * FF + f] = (f == 0) ? c0 : oc[1 + t * FF + f - 1];
        done[t * FF + f] = d ? 1 : 0;
        d = d || (oc[1 + t * FF + f] == EOS_ID);
    }
}

// ---------------------------------------------------------------------------
// h0 (fp32) + A0 = [h_hi | h_lo]
// ---------------------------------------------------------------------------
__global__ __launch_bounds__(256) void h0_kernel(const float* __restrict__ tctx,
                                                 const int* __restrict__ sent,
                                                 float* __restrict__ h,
                                                 __hip_bfloat16* __restrict__ A0) {
    int t = blockIdx.x;
    int tid = threadIdx.x;
    __shared__ int xt[CCH];
    if (tid < CCH) xt[tid] = sent[(t * CCH + tid) * 3 + 1];
    __syncthreads();
#pragma unroll
    for (int jj = 0; jj < 4; ++jj) {
        int j = tid + jj * 256;
        float s = 0.f;
#pragma unroll
        for (int c = 0; c < CCH; ++c) s += tctx[(size_t)xt[c] * HH + j];
        float hv = s * 0.125f;
        h[(size_t)t * HH + j] = hv;
        __hip_bfloat16 hi = __float2bfloat16(hv);
        __hip_bfloat16 lo = __float2bfloat16(hv - __bfloat162float(hi));
        A0[(size_t)t * KH + j]      = hi;
        A0[(size_t)t * KH + HH + j] = lo;
    }
}

// ---------------------------------------------------------------------------
// generic fp32 -> bf16 (n4 float4s, grid*256 == n4)
// ---------------------------------------------------------------------------
__global__ __launch_bounds__(256) void f2b_kernel(const float* __restrict__ src,
                                                  __hip_bfloat16* __restrict__ dst) {
    size_t base = ((size_t)blockIdx.x * 256 + threadIdx.x) * 4;
    float4 v = *(const float4*)(src + base);
    dst[base + 0] = __float2bfloat16(v.x);
    dst[base + 1] = __float2bfloat16(v.y);
    dst[base + 2] = __float2bfloat16(v.z);
    dst[base + 3] = __float2bfloat16(v.w);
}

// ---------------------------------------------------------------------------
// Bh[n][k]: k<1024 -> hi(Whh[n][k]); k>=1024 -> lo(Whh[n][k-1024])
// grid (8, 3072)
// ---------------------------------------------------------------------------
__global__ __launch_bounds__(256) void build_Bh(const float* __restrict__ Whh,
                                                __hip_bfloat16* __restrict__ Bh) {
    int k = blockIdx.x * 256 + threadIdx.x;
    int n = blockIdx.y;
    float wv = Whh[(size_t)n * HH + (k & (HH - 1))];
    __hip_bfloat16 hi = __float2bfloat16(wv);
    Bh[(size_t)n * KH + k] = (k < HH) ? hi : __float2bfloat16(wv - __bfloat162float(hi));
}

// ---------------------------------------------------------------------------
// Pipelined 128x128 MFMA GEMM, 4-slot LDS ring, prefetch depth 2,
// counted vmcnt. C = A(MxK)*B(NxK)^T (row-major, K contiguous), fp32 out.
// MODE 0: step GEMM  (linear A rows, k-part offsets from blockIdx.z, partial out)
// MODE 1: enc x-table (A rows gathered: emb_bf[sent char])
// MODE 2: dec x-table (A rows gathered: emb_bf[c_in])
// ---------------------------------------------------------------------------
template<int MODE>
__global__ __launch_bounds__(256) void gemm_pipe(const __hip_bfloat16* __restrict__ A, int lda,
                                                 const __hip_bfloat16* __restrict__ B, int ldb,
                                                 float* __restrict__ C,
                                                 const int* __restrict__ idsrc,
                                                 int NIT) {
    __shared__ __hip_bfloat16 As[4][128 * 32];
    __shared__ __hip_bfloat16 Bs[4][128 * 32];
    __shared__ int sids[128];

    const int tid = threadIdx.x;
    const int n0 = blockIdx.x * 128;
    const int m0 = blockIdx.y * 128;

    int Aoff = 0, Boff = 0;
    if (MODE == 0) {
        const int p = blockIdx.z;
        // p: 0:(0,0) 1:(512,512) 2:(1024,0) 3:(1536,512) 4:(0,1024) 5:(512,1536)
        Aoff = ((p == 2 || p == 3) ? 1024 : 0) + ((p & 1) ? 512 : 0);
        Boff = ((p >= 4) ? 1024 : 0) + ((p & 1) ? 512 : 0);
    }
    if (MODE > 0) {
        if (tid < 128) {
            int row = m0 + tid;
            int t = row & 255;
            int id;
            if (MODE == 1) { int c = row >> 8; id = idsrc[(t * CCH + c) * 3 + 2]; }
            else           { int f = row >> 8; id = idsrc[t * FF + f]; }
            sids[tid] = id;
        }
        __syncthreads();
    }

    const int srow = tid >> 2, skq = tid & 3;

    const int l = tid & 63;
    const int w = tid >> 6;
    const int wr = (w >> 1) * 64, wc = (w & 1) * 64;
    const int fra = ((wr + (l & 15)) << 5) + ((l >> 4) << 3);
    const int frb = ((wc + (l & 15)) << 5) + ((l >> 4) << 3);

    f32x4 acc[4][4];
#pragma unroll
    for (int i = 0; i < 4; ++i)
#pragma unroll
        for (int j = 0; j < 4; ++j) acc[i][j] = (f32x4){0.f, 0.f, 0.f, 0.f};

    auto stage = [&](int slot, int it) {
        const int k0 = it * 32;
        const __hip_bfloat16 *ga0, *ga1;
        if (MODE == 0) {
            ga0 = A + (size_t)(m0 + srow) * lda + Aoff + k0 + skq * 8;
            ga1 = A + (size_t)(m0 + 64 + srow) * lda + Aoff + k0 + skq * 8;
        } else {
            ga0 = A + (size_t)sids[srow] * lda + k0 + skq * 8;
            ga1 = A + (size_t)sids[64 + srow] * lda + k0 + skq * 8;
        }
        const __hip_bfloat16* gb0 = B + (size_t)(n0 + srow) * ldb + Boff + k0 + skq * 8;
        const __hip_bfloat16* gb1 = B + (size_t)(n0 + 64 + srow) * ldb + Boff + k0 + skq * 8;
        __hip_bfloat16* lA = &As[slot][tid * 8];
        __hip_bfloat16* lB = &Bs[slot][tid * 8];
        gload_lds16(ga0, lA);
        gload_lds16(ga1, lA + 2048);
        gload_lds16(gb0, lB);
        gload_lds16(gb1, lB + 2048);
    };

    stage(0, 0);
    stage(1, 1);

    for (int it = 0; it < NIT; ++it) {
        if (it + 2 < NIT) stage((it + 2) & 3, it + 2);
        int ahead = NIT - 1 - it; if (ahead > 2) ahead = 2;
        if (ahead >= 2)      asm volatile("s_waitcnt vmcnt(8)" ::: "memory");
        else if (ahead == 1) asm volatile("s_waitcnt vmcnt(4)" ::: "memory");
        else                 asm volatile("s_waitcnt vmcnt(0)" ::: "memory");
        __builtin_amdgcn_s_barrier();
        __builtin_amdgcn_sched_barrier(0);

        const __hip_bfloat16* cA = As[it & 3];
        const __hip_bfloat16* cB = Bs[it & 3];
        bf16x8 af[4], bfv[4];
#pragma unroll
        for (int fm = 0; fm < 4; ++fm) af[fm] = *(const bf16x8*)&cA[fra + fm * 512];
#pragma unroll
        for (int fn = 0; fn < 4; ++fn) bfv[fn] = *(const bf16x8*)&cB[frb + fn * 512];
#pragma unroll
        for (int fm = 0; fm < 4; ++fm)
#pragma unroll
            for (int fn = 0; fn < 4; ++fn)
                acc[fm][fn] = __builtin_amdgcn_mfma_f32_16x16x32_bf16(af[fm], bfv[fn], acc[fm][fn], 0, 0, 0);
    }

    float* Cp = (MODE == 0) ? (C + (size_t)blockIdx.z * TT * NG) : C;
    const int colb = wc + (l & 15);
    const int rb   = wr + ((l >> 4) << 2);
#pragma unroll
    for (int fm = 0; fm < 4; ++fm)
#pragma unroll
        for (int fn = 0; fn < 4; ++fn)
#pragma unroll
            for (int q = 0; q < 4; ++q)
                Cp[(size_t)(m0 + rb + fm * 16 + q) * NG + n0 + colb + fn * 16] = acc[fm][fn][q];
}

// ---------------------------------------------------------------------------
// GRU epilogue: sum 6 k-part partials + gi table + biases -> gates -> h_out,
// A_next = [hi|lo], hs slice (dec). grid 256 (t) x 256 thr.
// ---------------------------------------------------------------------------
__global__ __launch_bounds__(256) void gru_epi2(const float* __restrict__ gp,
                                                const float* __restrict__ gi,
                                                const float* __restrict__ bih,
                                                const float* __restrict__ bhh,
                                                const float* __restrict__ h_in,
                                                float* __restrict__ h_out,
                                                __hip_bfloat16* __restrict__ A_next,
                                                __hip_bfloat16* __restrict__ hs_out,
                                                const unsigned char* __restrict__ dflags, int doff) {
    int t = blockIdx.x, tid = threadIdx.x;
    unsigned char dn = dflags ? dflags[t * FF + doff] : (unsigned char)0;
    const size_t base = (size_t)t * NG;
#pragma unroll
    for (int jj = 0; jj < 4; ++jj) {
        int j = tid + jj * 256;
        float ghr = 0.f, ghz = 0.f, ghn = 0.f;
#pragma unroll
        for (int p = 0; p < 6; ++p) {
            const float* g = gp + (size_t)p * TT * NG + base;
            ghr += g[j];
            ghz += g[HH + j];
            ghn += g[2 * HH + j];
        }
        float gir = gi[base + j], giz = gi[base + HH + j], gin = gi[base + 2 * HH + j];
        float r = 1.f / (1.f + __expf(-(gir + bih[j] + ghr + bhh[j])));
        float z = 1.f / (1.f + __expf(-(giz + bih[HH + j] + ghz + bhh[HH + j])));
        float n = tanhf(gin + bih[2 * HH + j] + r * (ghn + bhh[2 * HH + j]));
        float hold = h_in[(size_t)t * HH + j];
        float hv = (1.f - z) * n + z * hold;
        if (dn) hv = hold;
        h_out[(size_t)t * HH + j] = hv;
        __hip_bfloat16 hi = __float2bfloat16(hv);
        __hip_bfloat16 lo = __float2bfloat16(hv - __bfloat162float(hi));
        if (A_next) {
            A_next[(size_t)t * KH + j]      = hi;
            A_next[(size_t)t * KH + HH + j] = lo;
        }
        if (hs_out) hs_out[(size_t)t * HH + j] = hi;
    }
}

// ---------------------------------------------------------------------------
// scores (round-2 validated): 128x128 MFMA, single-buffer 2-barrier core
// ---------------------------------------------------------------------------
__global__ __launch_bounds__(256) void scores_mfma(const __hip_bfloat16* __restrict__ hsb,
                                                   const __hip_bfloat16* __restrict__ Wb,
                                                   const float* __restrict__ bout,
                                                   const int* __restrict__ oc,
                                                   float* __restrict__ out) {
    __shared__ __hip_bfloat16 As[128 * 32], Bs[128 * 32];
    int bid = blockIdx.x;
    int sid = (bid & 7) * 632 + (bid >> 3);      // 5056 = 8*632, bijective
    int bx = sid % 79, by = sid / 79;
    int n0 = bx * 128, m0 = by * 128;

    const int tid = threadIdx.x;
    const int l = tid & 63;
    const int w = tid >> 6;
    const int wr = (w >> 1) * 64, wc = (w & 1) * 64;
    const int srow = tid >> 2, skq = tid & 3;

    f32x4 acc[4][4];
#pragma unroll
    for (int i = 0; i < 4; ++i)
#pragma unroll
        for (int j = 0; j < 4; ++j) acc[i][j] = (f32x4){0.f, 0.f, 0.f, 0.f};

    const int ar0 = m0 + srow, ar1 = m0 + 64 + srow;
    int br0 = n0 + srow, br1 = n0 + 64 + srow;
    br0 = (br0 > VV - 1) ? VV - 1 : br0;
    br1 = (br1 > VV - 1) ? VV - 1 : br1;
    const __hip_bfloat16* gA0 = hsb + (size_t)ar0 * HH + skq * 8;
    const __hip_bfloat16* gA1 = hsb + (size_t)ar1 * HH + skq * 8;
    const __hip_bfloat16* gB0 = Wb + (size_t)br0 * HH + skq * 8;
    const __hip_bfloat16* gB1 = Wb + (size_t)br1 * HH + skq * 8;
    __hip_bfloat16* lA = As + tid * 8;
    __hip_bfloat16* lB = Bs + tid * 8;
    const int fra = ((wr + (l & 15)) << 5) + ((l >> 4) << 3);
    const int frb = ((wc + (l & 15)) << 5) + ((l >> 4) << 3);

    for (int k0 = 0; k0 < HH; k0 += 32) {
        __syncthreads();
        gload_lds16(gA0 + k0, lA);
        gload_lds16(gA1 + k0, lA + 2048);
        gload_lds16(gB0 + k0, lB);
        gload_lds16(gB1 + k0, lB + 2048);
        __syncthreads();
        bf16x8 af[4], bfv[4];
#pragma unroll
        for (int fm = 0; fm < 4; ++fm) af[fm] = *(const bf16x8*)&As[fra + fm * 512];
#pragma unroll
        for (int fn = 0; fn < 4; ++fn) bfv[fn] = *(const bf16x8*)&Bs[frb + fn * 512];
#pragma unroll
        for (int fm = 0; fm < 4; ++fm)
#pragma unroll
            for (int fn = 0; fn < 4; ++fn)
                acc[fm][fn] = __builtin_amdgcn_mfma_f32_16x16x32_bf16(af[fm], bfv[fn], acc[fm][fn], 0, 0, 0);
    }

    const bool zf = (oc[0] == EOS_ID);
    const int colb = wc + (l & 15);
    const int rb   = wr + ((l >> 4) << 2);
#pragma unroll
    for (int fn = 0; fn < 4; ++fn) {
        int v = n0 + colb + fn * 16;
        if (v < VV) {
            float bb = bout[v];
#pragma unroll
            for (int fm = 0; fm < 4; ++fm) {
#pragma unroll
                for (int q = 0; q < 4; ++q) {
                    int m = m0 + rb + fm * 16 + q;
                    int f = m >> 8, t = m & 255;
                    out[(size_t)(t * FF + f) * VV + v] = zf ? 0.f : (acc[fm][fn][q] + bb);
                }
            }
        }
    }
}

// ---------------------------------------------------------------------------
extern "C" void kernel_launch(void* const* d_in, const int* in_sizes, int n_in,
                              void* d_out, int out_size, void* d_ws, size_t ws_size,
                              hipStream_t stream) {
    (void)in_sizes; (void)n_in; (void)ws_size;

    const float* token_ctx = (const float*)d_in[0];
    const float* emb       = (const float*)d_in[1];
    const float* eWih      = (const float*)d_in[2];
    const float* eWhh      = (const float*)d_in[3];
    const float* ebih      = (const float*)d_in[4];
    const float* ebhh      = (const float*)d_in[5];
    const float* dWih      = (const float*)d_in[6];
    const float* dWhh      = (const float*)d_in[7];
    const float* dbih      = (const float*)d_in[8];
    const float* dbhh      = (const float*)d_in[9];
    const float* Wout      = (const float*)d_in[10];
    const float* bout      = (const float*)d_in[11];
    const int*   sent      = (const int*)d_in[12];
    const int*   ochars    = (const int*)d_in[13];
    float* out = (float*)d_out;

    // ---- ws layout (~41 MB) ----
    char* w = (char*)d_ws;
    float* hA = (float*)w;                      w += (size_t)TT * HH * 4;
    float* hB = (float*)w;                      w += (size_t)TT * HH * 4;
    __hip_bfloat16* A0 = (__hip_bfloat16*)w;    w += (size_t)TT * KH * 2;
    __hip_bfloat16* A1 = (__hip_bfloat16*)w;    w += (size_t)TT * KH * 2;
    __hip_bfloat16* hsb = (__hip_bfloat16*)w;   w += (size_t)FF * TT * HH * 2;
    __hip_bfloat16* Woutb = (__hip_bfloat16*)w; w += (size_t)VV * HH * 2;
    int* c_in = (int*)w;                        w += (size_t)TT * FF * 4;
    unsigned char* done = (unsigned char*)w;

    // ---- d_out tail scratch (dead until scores_mfma) ----
    char* tail = (char*)d_out + (size_t)out_size * 4;
    tail -= (size_t)NG * KH * 2;          __hip_bfloat16* Bh_e = (__hip_bfloat16*)tail;
    tail -= (size_t)NG * KH * 2;          __hip_bfloat16* Bh_d = (__hip_bfloat16*)tail;
    tail -= (size_t)CCH * TT * NG * 4;    float* gi_enc = (float*)tail;
    tail -= (size_t)FF * TT * NG * 4;     float* gi_dec = (float*)tail;
    tail -= (size_t)6 * TT * NG * 4;      float* gp = (float*)tail;
    tail -= (size_t)VV * EE * 2;          __hip_bfloat16* emb_bf = (__hip_bfloat16*)tail;
    tail -= (size_t)NG * EE * 2;          __hip_bfloat16* Wihb_e = (__hip_bfloat16*)tail;
    tail -= (size_t)NG * EE * 2;          __hip_bfloat16* Wihb_d = (__hip_bfloat16*)tail;

    // ---- prep & conversions ----
    prep_kernel<<<1, 256, 0, stream>>>(ochars, c_in, done);
    h0_kernel<<<TT, 256, 0, stream>>>(token_ctx, sent, hA, A0);
    f2b_kernel<<<(VV * EE) / 4 / 256, 256, 0, stream>>>(emb, emb_bf);
    f2b_kernel<<<(NG * EE) / 4 / 256, 256, 0, stream>>>(eWih, Wihb_e);
    f2b_kernel<<<(NG * EE) / 4 / 256, 256, 0, stream>>>(dWih, Wihb_d);
    f2b_kernel<<<(VV * HH) / 4 / 256, 256, 0, stream>>>(Wout, Woutb);
    build_Bh<<<dim3(8, NG), 256, 0, stream>>>(eWhh, Bh_e);
    build_Bh<<<dim3(8, NG), 256, 0, stream>>>(dWhh, Bh_d);

    // ---- x-side tables: gi = emb_bf[ids] @ Wih^T (fp32) ----
    gemm_pipe<1><<<dim3(24, 16), 256, 0, stream>>>(emb_bf, EE, Wihb_e, EE, gi_enc, sent, 8);
    gemm_pipe<2><<<dim3(24, 64), 256, 0, stream>>>(emb_bf, EE, Wihb_d, EE, gi_dec, c_in, 8);

    // ---- recurrent chain ----
    dim3 sg(24, 2, 6);
    const float* hcur = hA; float* hnext = hB;
    __hip_bfloat16* Acur = A0; __hip_bfloat16* Anext = A1;
    for (int c = 0; c < CCH; ++c) {
        gemm_pipe<0><<<sg, 256, 0, stream>>>(Acur, KH, Bh_e, KH, gp, nullptr, 16);
        gru_epi2<<<TT, 256, 0, stream>>>(gp, gi_enc + (size_t)c * TT * NG, ebih, ebhh,
                                         hcur, hnext, Anext, nullptr, nullptr, 0);
        const float* tmp = hcur; hcur = hnext; hnext = (float*)tmp;
        __hip_bfloat16* tA = Acur; Acur = Anext; Anext = tA;
    }
    for (int f = 0; f < FF; ++f) {
        gemm_pipe<0><<<sg, 256, 0, stream>>>(Acur, KH, Bh_d, KH, gp, nullptr, 16);
        __hip_bfloat16* An = (f < FF - 1) ? Anext : nullptr;
        gru_epi2<<<TT, 256, 0, stream>>>(gp, gi_dec + (size_t)f * TT * NG, dbih, dbhh,
                                         hcur, hnext, An,
                                         hsb + (size_t)f * TT * HH, done, f);
        const float* tmp = hcur; hcur = hnext; hnext = (float*)tmp;
        __hip_bfloat16* tA = Acur; Acur = Anext; Anext = tA;
    }

    // ---- scores ----
    scores_mfma<<<5056, 256, 0, stream>>>(hsb, Woutb, bout, ochars, out);
}